// Round 2
// baseline (1853.172 us; speedup 1.0000x reference)
//
#include <hip/hip_runtime.h>

#define NN 2
#define LL 8192
#define HH 8
#define EE 64
#define MM 64
#define TT 128
#define CC (LL/TT)   // 64 chunks
#define FEPS 1e-6f

__device__ __forceinline__ float featf(float x) {
    // elu(x) + 1:  x>0 -> x+1 ; x<=0 -> exp(x)
    return x > 0.f ? x + 1.f : __expf(x);
}

// ---------------------------------------------------------------------------
// Kernel 1: per-(n,h,chunk) partial sums:  kv_chunk[e][m] = sum_t K[t][e]*V[t][m]
//           ksum_chunk[e] = sum_t K[t][e]
// grid = N*H*C, block = 256
// ---------------------------------------------------------------------------
__global__ __launch_bounds__(256) void k_chunk_sums(
    const float* __restrict__ keys, const float* __restrict__ values,
    const float* __restrict__ mask,
    float* __restrict__ kv_chunk, float* __restrict__ ksum_chunk)
{
    __shared__ float kS[TT][EE];   // 32 KB
    __shared__ float vS[TT][MM];   // 32 KB

    const int b  = blockIdx.x;          // ((n*HH+h)*CC + c)
    const int c  = b % CC;
    const int nh = b / CC;
    const int h  = nh % HH;
    const int n  = nh / HH;
    const int tid = threadIdx.x;

    const size_t rowstride = (size_t)HH * EE;                    // 512 floats
    const size_t base = ((size_t)(n*LL + c*TT) * HH + h) * EE;

    #pragma unroll
    for (int kk = 0; kk < 8; ++kk) {
        int j   = tid + kk*256;      // float4 unit 0..2047
        int row = j >> 4;
        int c4  = j & 15;
        float4 k4 = *(const float4*)(keys   + base + (size_t)row*rowstride + c4*4);
        float4 v4 = *(const float4*)(values + base + (size_t)row*rowstride + c4*4);
        float mv  = mask[n*LL + c*TT + row];
        float4 f;
        f.x = featf(k4.x)*mv; f.y = featf(k4.y)*mv;
        f.z = featf(k4.z)*mv; f.w = featf(k4.w)*mv;
        *(float4*)&kS[row][c4*4] = f;
        *(float4*)&vS[row][c4*4] = v4;
    }
    __syncthreads();

    const int e  = tid & 63;
    const int mq = tid >> 6;
    const int m0 = mq * 16;

    float acc[16];
    #pragma unroll
    for (int i = 0; i < 16; ++i) acc[i] = 0.f;

    for (int t = 0; t < TT; ++t) {
        float kv = kS[t][e];
        #pragma unroll
        for (int i4 = 0; i4 < 4; ++i4) {
            float4 v4 = *(const float4*)&vS[t][m0 + i4*4];
            acc[i4*4+0] += kv * v4.x;
            acc[i4*4+1] += kv * v4.y;
            acc[i4*4+2] += kv * v4.z;
            acc[i4*4+3] += kv * v4.w;
        }
    }

    float* dst = kv_chunk + (size_t)b*EE*MM + e*MM + m0;
    #pragma unroll
    for (int i4 = 0; i4 < 4; ++i4) {
        float4 o;
        o.x = acc[i4*4+0]; o.y = acc[i4*4+1];
        o.z = acc[i4*4+2]; o.w = acc[i4*4+3];
        *(float4*)(dst + i4*4) = o;
    }

    if (tid < EE) {
        float s = 0.f;
        for (int t = 0; t < TT; ++t) s += kS[t][tid];
        ksum_chunk[(size_t)b*EE + tid] = s;
    }
}

// ---------------------------------------------------------------------------
// Kernel 2a: in-place exclusive prefix-scan of kv_chunk over chunks, per (n,h).
// Each thread owns one state element; all 64 chunk values loaded up-front
// (independent loads -> one latency round), scanned in registers, stored back.
// grid = N*H*16, block = 256   (16*256 = 4096 state elems)
// ---------------------------------------------------------------------------
__global__ __launch_bounds__(256) void k_scan_kv(
    float* __restrict__ kv_chunk, float* __restrict__ kv_total)
{
    const int part = blockIdx.x & 15;
    const int nh   = blockIdx.x >> 4;
    const int i    = part*256 + threadIdx.x;

    float* bufb = kv_chunk + (size_t)nh*CC*EE*MM + i;

    float vals[CC];
    #pragma unroll
    for (int c = 0; c < CC; ++c) vals[c] = bufb[(size_t)c*EE*MM];

    float run = 0.f;
    #pragma unroll
    for (int c = 0; c < CC; ++c) {
        float v = vals[c];
        bufb[(size_t)c*EE*MM] = run;   // exclusive prefix
        run += v;
    }
    kv_total[(size_t)nh*EE*MM + i] = run;
}

// ---------------------------------------------------------------------------
// Kernel 2b: same scan for ksum_chunk. grid = N*H, block = 64.
// ---------------------------------------------------------------------------
__global__ __launch_bounds__(64) void k_scan_ksum(
    float* __restrict__ ksum_chunk, float* __restrict__ ksum_total)
{
    const int nh = blockIdx.x;
    const int e  = threadIdx.x;
    float* bufb = ksum_chunk + (size_t)nh*CC*EE + e;

    float vals[CC];
    #pragma unroll
    for (int c = 0; c < CC; ++c) vals[c] = bufb[c*EE];

    float run = 0.f;
    #pragma unroll
    for (int c = 0; c < CC; ++c) {
        float v = vals[c];
        bufb[c*EE] = run;
        run += v;
    }
    ksum_total[nh*EE + e] = run;
}

// ---------------------------------------------------------------------------
// Kernel 3: per-(n,h,chunk) outputs.
//   causal: out_c[t][m] = (sum_{s<=t} (q_t.k_s) v_s[m] + sum_e q_t[e]*Sprev[e][m]) * Zc
//           Zc = 1/(q_t . (ksum_prefix + intra-cumsum K) + eps)
//   non-causal: out_n[t][m] = (sum_e q_t[e]*KVtot[e][m]) * Z,  Z = 1/(q_t.Ktot + eps)
// grid = N*H*C, block = 256: tid = mh*128 + t,  mh in {0,1} covers m-halves.
// ---------------------------------------------------------------------------
__global__ __launch_bounds__(256) void k_output(
    const float* __restrict__ qin, const float* __restrict__ kin,
    const float* __restrict__ vin, const float* __restrict__ mask,
    const float* __restrict__ kv_prefix, const float* __restrict__ ksum_prefix,
    const float* __restrict__ kv_total,  const float* __restrict__ ksum_total,
    float* __restrict__ outV, float* __restrict__ outVc)
{
    __shared__ float kS[TT][EE];   // 32 KB
    __shared__ float vS[TT][MM];   // 32 KB
    __shared__ float sS[EE][MM];   // 16 KB  exclusive-prefix state S[e][m]
    __shared__ float gS[EE][MM];   // 16 KB  total KV[e][m]
    __shared__ float ksp[EE];
    __shared__ float kst[EE];

    const int b  = blockIdx.x;
    const int c  = b % CC;
    const int nh = b / CC;
    const int h  = nh % HH;
    const int n  = nh / HH;
    const int tid = threadIdx.x;
    const int t  = tid & 127;
    const int mh = tid >> 7;
    const int m0 = mh * 32;

    const size_t rowstride = (size_t)HH * EE;
    const size_t base = ((size_t)(n*LL + c*TT) * HH + h) * EE;

    // stage K (featured+masked) and V
    #pragma unroll
    for (int kk = 0; kk < 8; ++kk) {
        int j   = tid + kk*256;
        int row = j >> 4;
        int c4  = j & 15;
        float4 k4 = *(const float4*)(kin + base + (size_t)row*rowstride + c4*4);
        float4 v4 = *(const float4*)(vin + base + (size_t)row*rowstride + c4*4);
        float mv  = mask[n*LL + c*TT + row];
        float4 f;
        f.x = featf(k4.x)*mv; f.y = featf(k4.y)*mv;
        f.z = featf(k4.z)*mv; f.w = featf(k4.w)*mv;
        *(float4*)&kS[row][c4*4] = f;
        *(float4*)&vS[row][c4*4] = v4;
    }
    // stage S_prefix and KV_total
    {
        const float4* sp = (const float4*)(kv_prefix + (size_t)b*EE*MM);
        const float4* gp = (const float4*)(kv_total + (size_t)nh*EE*MM);
        #pragma unroll
        for (int kk = 0; kk < 4; ++kk) {
            int j = tid + kk*256;
            ((float4*)sS)[j] = sp[j];
            ((float4*)gS)[j] = gp[j];
        }
    }
    if (tid < EE) {
        ksp[tid] = ksum_prefix[(size_t)b*EE + tid];
        kst[tid] = ksum_total[(size_t)nh*EE + tid];
    }
    __syncthreads();

    // Q row (featured) into registers
    float q[EE];
    {
        const float* qrow = qin + base + (size_t)t*rowstride;
        #pragma unroll
        for (int e4 = 0; e4 < 16; ++e4) {
            float4 q4 = *(const float4*)(qrow + e4*4);
            q[e4*4+0] = featf(q4.x);
            q[e4*4+1] = featf(q4.y);
            q[e4*4+2] = featf(q4.z);
            q[e4*4+3] = featf(q4.w);
        }
    }

    float accC[32], accN[32];
    #pragma unroll
    for (int i = 0; i < 32; ++i) { accC[i] = 0.f; accN[i] = 0.f; }
    float zc = 0.f, z = 0.f;

    // inter-chunk + non-causal: fully unrolled over e (q[] must stay in regs)
    #pragma unroll
    for (int e = 0; e < EE; ++e) {
        float qe = q[e];
        zc += qe * ksp[e];
        z  += qe * kst[e];
        #pragma unroll
        for (int i4 = 0; i4 < 8; ++i4) {
            float4 s4 = *(const float4*)&sS[e][m0 + i4*4];
            float4 g4 = *(const float4*)&gS[e][m0 + i4*4];
            accC[i4*4+0] += qe * s4.x;  accN[i4*4+0] += qe * g4.x;
            accC[i4*4+1] += qe * s4.y;  accN[i4*4+1] += qe * g4.y;
            accC[i4*4+2] += qe * s4.z;  accN[i4*4+2] += qe * g4.z;
            accC[i4*4+3] += qe * s4.w;  accN[i4*4+3] += qe * g4.w;
        }
    }

    // intra-chunk causal part. t-ranges are wave-uniform: lanes 0..63 of a wave
    // are either all t<64 or all t>=64, so s_end is wave-uniform.
    const int s_end = (t & 64) ? TT : 64;
    for (int s = 0; s < s_end; ++s) {
        float a0 = 0.f, a1 = 0.f, a2 = 0.f, a3 = 0.f;   // 4-way ILP dot
        #pragma unroll
        for (int e4 = 0; e4 < 16; ++e4) {
            float4 k4 = *(const float4*)&kS[s][e4*4];
            a0 += q[e4*4+0] * k4.x;
            a1 += q[e4*4+1] * k4.y;
            a2 += q[e4*4+2] * k4.z;
            a3 += q[e4*4+3] * k4.w;
        }
        float a  = (a0 + a1) + (a2 + a3);
        float am = (s <= t) ? a : 0.f;
        zc += am;
        #pragma unroll
        for (int i4 = 0; i4 < 8; ++i4) {
            float4 v4 = *(const float4*)&vS[s][m0 + i4*4];
            accC[i4*4+0] += am * v4.x;
            accC[i4*4+1] += am * v4.y;
            accC[i4*4+2] += am * v4.z;
            accC[i4*4+3] += am * v4.w;
        }
    }

    const float zci = 1.f / (zc + FEPS);
    const float zni = 1.f / (z  + FEPS);

    const size_t obase = ((size_t)(n*LL + c*TT + t) * HH + h) * MM + m0;
    #pragma unroll
    for (int i4 = 0; i4 < 8; ++i4) {
        float4 on, oc;
        on.x = accN[i4*4+0]*zni; on.y = accN[i4*4+1]*zni;
        on.z = accN[i4*4+2]*zni; on.w = accN[i4*4+3]*zni;
        oc.x = accC[i4*4+0]*zci; oc.y = accC[i4*4+1]*zci;
        oc.z = accC[i4*4+2]*zci; oc.w = accC[i4*4+3]*zci;
        *(float4*)(outV  + obase + i4*4) = on;
        *(float4*)(outVc + obase + i4*4) = oc;
    }
}

// ---------------------------------------------------------------------------
extern "C" void kernel_launch(void* const* d_in, const int* in_sizes, int n_in,
                              void* d_out, int out_size, void* d_ws, size_t ws_size,
                              hipStream_t stream) {
    const float* q    = (const float*)d_in[0];
    const float* k    = (const float*)d_in[1];
    const float* v    = (const float*)d_in[2];
    const float* mask = (const float*)d_in[3];

    float* outV  = (float*)d_out;                       // non-causal branch (output 0)
    float* outVc = outV + (size_t)NN*LL*HH*MM;          // causal branch (output 1)

    float* kv_chunk   = (float*)d_ws;                               // N*H*C*E*M
    float* ksum_chunk = kv_chunk   + (size_t)NN*HH*CC*EE*MM;        // N*H*C*E
    float* kv_total   = ksum_chunk + (size_t)NN*HH*CC*EE;           // N*H*E*M
    float* ksum_total = kv_total   + (size_t)NN*HH*EE*MM;           // N*H*E

    k_chunk_sums<<<NN*HH*CC, 256, 0, stream>>>(k, v, mask, kv_chunk, ksum_chunk);
    k_scan_kv  <<<NN*HH*16, 256, 0, stream>>>(kv_chunk, kv_total);
    k_scan_ksum<<<NN*HH,     64, 0, stream>>>(ksum_chunk, ksum_total);
    k_output   <<<NN*HH*CC, 256, 0, stream>>>(q, k, v, mask,
                                              kv_chunk, ksum_chunk,
                                              kv_total, ksum_total,
                                              outV, outVc);
}

// Round 5
// 197.941 us; speedup vs baseline: 9.3623x; 9.3623x over previous
//
#include <hip/hip_runtime.h>

#define NN 2
#define LL 8192
#define HH 8
#define EE 64
#define MM 64
#define TT 128
#define CC (LL/TT)   // 64 chunks
#define FEPS 1e-6f

typedef __attribute__((ext_vector_type(8)))  short short8;
typedef __attribute__((ext_vector_type(16))) float f32x16;

__device__ __forceinline__ float featf(float x) {
    return x > 0.f ? x + 1.f : __expf(x);   // elu(x)+1
}

__device__ __forceinline__ unsigned short f2bf(float x) {
    union { float f; unsigned u; } v; v.f = x;
    unsigned r = v.u + 0x7FFF + ((v.u >> 16) & 1);   // RNE
    return (unsigned short)(r >> 16);
}

__device__ __forceinline__ unsigned cvtpk(float lo, float hi) {
    unsigned r;
    asm volatile("v_cvt_pk_bf16_f32 %0, %1, %2" : "=v"(r) : "v"(lo), "v"(hi));
    return r;
}

__device__ __forceinline__ void plswap(unsigned &a, unsigned &b) {
    // new a = {lanes0-31: a, lanes32-63: b's lanes0-31}; new b = {a's lanes32-63, b's lanes32-63}
    asm volatile("v_permlane32_swap_b32 %0, %1" : "+v"(a), "+v"(b));
}

#define ZERO16 {0.f,0.f,0.f,0.f,0.f,0.f,0.f,0.f,0.f,0.f,0.f,0.f,0.f,0.f,0.f,0.f}

// XOR-swizzled LDS index macros (u16 units; XOR of idx bits 3-5 = 16B groups)
#define KT_IDX(s,e) ((((s)*64)  + (e)) ^ (((s)&7)<<3))
#define VT_IDX(m,s) ((((m)*128) + (s)) ^ (((m)&7)<<3))
#define ST_IDX(m,e) ((((m)*64)  + (e)) ^ (((m)&7)<<3))

// ---------------------------------------------------------------------------
// Kernel 1: per-(n,h,chunk) partial sums:  kv_chunk[e][m] = sum_t K[t][e]*V[t][m]
//           ksum_chunk[e] = sum_t K[t][e]
// ---------------------------------------------------------------------------
__global__ __launch_bounds__(256) void k_chunk_sums(
    const float* __restrict__ keys, const float* __restrict__ values,
    const float* __restrict__ mask,
    float* __restrict__ kv_chunk, float* __restrict__ ksum_chunk)
{
    __shared__ float kS[TT][EE];
    __shared__ float vS[TT][MM];

    const int b  = blockIdx.x;
    const int c  = b % CC;
    const int nh = b / CC;
    const int h  = nh % HH;
    const int n  = nh / HH;
    const int tid = threadIdx.x;

    const size_t rowstride = (size_t)HH * EE;
    const size_t base = ((size_t)(n*LL + c*TT) * HH + h) * EE;

    #pragma unroll
    for (int kk = 0; kk < 8; ++kk) {
        int j   = tid + kk*256;
        int row = j >> 4;
        int c4  = j & 15;
        float4 k4 = *(const float4*)(keys   + base + (size_t)row*rowstride + c4*4);
        float4 v4 = *(const float4*)(values + base + (size_t)row*rowstride + c4*4);
        float mv  = mask[n*LL + c*TT + row];
        float4 f;
        f.x = featf(k4.x)*mv; f.y = featf(k4.y)*mv;
        f.z = featf(k4.z)*mv; f.w = featf(k4.w)*mv;
        *(float4*)&kS[row][c4*4] = f;
        *(float4*)&vS[row][c4*4] = v4;
    }
    __syncthreads();

    const int e  = tid & 63;
    const int mq = tid >> 6;
    const int m0 = mq * 16;

    float acc[16];
    #pragma unroll
    for (int i = 0; i < 16; ++i) acc[i] = 0.f;

    for (int t = 0; t < TT; ++t) {
        float kv = kS[t][e];
        #pragma unroll
        for (int i4 = 0; i4 < 4; ++i4) {
            float4 v4 = *(const float4*)&vS[t][m0 + i4*4];
            acc[i4*4+0] += kv * v4.x;
            acc[i4*4+1] += kv * v4.y;
            acc[i4*4+2] += kv * v4.z;
            acc[i4*4+3] += kv * v4.w;
        }
    }

    float* dst = kv_chunk + (size_t)b*EE*MM + e*MM + m0;
    #pragma unroll
    for (int i4 = 0; i4 < 4; ++i4) {
        float4 o;
        o.x = acc[i4*4+0]; o.y = acc[i4*4+1];
        o.z = acc[i4*4+2]; o.w = acc[i4*4+3];
        *(float4*)(dst + i4*4) = o;
    }

    if (tid < EE) {
        float s = 0.f;
        for (int t = 0; t < TT; ++t) s += kS[t][tid];
        ksum_chunk[(size_t)b*EE + tid] = s;
    }
}

// ---------------------------------------------------------------------------
// Kernel 2a/2b: exclusive prefix scans
// ---------------------------------------------------------------------------
__global__ __launch_bounds__(256) void k_scan_kv(
    float* __restrict__ kv_chunk, float* __restrict__ kv_total)
{
    const int part = blockIdx.x & 15;
    const int nh   = blockIdx.x >> 4;
    const int i    = part*256 + threadIdx.x;

    float* bufb = kv_chunk + (size_t)nh*CC*EE*MM + i;

    float vals[CC];
    #pragma unroll
    for (int c = 0; c < CC; ++c) vals[c] = bufb[(size_t)c*EE*MM];

    float run = 0.f;
    #pragma unroll
    for (int c = 0; c < CC; ++c) {
        float v = vals[c];
        bufb[(size_t)c*EE*MM] = run;
        run += v;
    }
    kv_total[(size_t)nh*EE*MM + i] = run;
}

__global__ __launch_bounds__(64) void k_scan_ksum(
    float* __restrict__ ksum_chunk, float* __restrict__ ksum_total)
{
    const int nh = blockIdx.x;
    const int e  = threadIdx.x;
    float* bufb = ksum_chunk + (size_t)nh*CC*EE + e;

    float vals[CC];
    #pragma unroll
    for (int c = 0; c < CC; ++c) vals[c] = bufb[c*EE];

    float run = 0.f;
    #pragma unroll
    for (int c = 0; c < CC; ++c) {
        float v = vals[c];
        bufb[c*EE] = run;
        run += v;
    }
    ksum_total[nh*EE + e] = run;
}

// ---------------------------------------------------------------------------
// Kernel 3 (MFMA): per-(n,h,chunk). 4 waves; wave w owns t = w + 4*(lane&31).
// QK^T: D = mfma(Kfrag, Qfrag) -> D[s_local][t].  Mask s<=t on fp32 D regs;
// cvt_pk + permlane32_swap -> P as PV A-operand.  PV + inter-chunk
// (Q·S_prefix, Q·KV_total) via mfma_f32_32x32x16_bf16.
// Zc = masked-score row sums + fp32 q·ksum_prefix;  Z = fp32 q·ksum_total.
// ---------------------------------------------------------------------------
__global__ __launch_bounds__(256) void k_output(
    const float* __restrict__ qin, const float* __restrict__ kin,
    const float* __restrict__ vin, const float* __restrict__ mask,
    const float* __restrict__ kv_prefix, const float* __restrict__ ksum_prefix,
    const float* __restrict__ kv_total,  const float* __restrict__ ksum_total,
    float* __restrict__ outV, float* __restrict__ outVc)
{
    __shared__ unsigned short kT[TT*EE];   // [s][e] bf16, swizzled, 16 KB
    __shared__ unsigned short vT[MM*TT];   // [m][s] bf16, swizzled, 16 KB
    __shared__ unsigned short sT[MM*EE];   // [m][e] bf16 (S_prefix^T), 8 KB
    __shared__ unsigned short gT[MM*EE];   // [m][e] bf16 (KV_total^T), 8 KB
    __shared__ float kspS[EE];
    __shared__ float kstS[EE];

    const int b  = blockIdx.x;
    const int c  = b % CC;
    const int nh = b / CC;
    const int h  = nh % HH;
    const int n  = nh / HH;
    const int tid = threadIdx.x;

    const size_t rowstride = (size_t)HH * EE;
    const size_t base = ((size_t)(n*LL + c*TT) * HH + h) * EE;

    // ---- cooperative staging ----
    {
        const int s2   = tid >> 1;        // 0..127
        const int half = tid & 1;         // e/m half
        const float mv = mask[n*LL + c*TT + s2];
        const float* krow = kin + base + (size_t)s2*rowstride + half*32;
        const float* vrow = vin + base + (size_t)s2*rowstride + half*32;
        #pragma unroll
        for (int i = 0; i < 8; ++i) {
            float4 k4 = *(const float4*)(krow + i*4);
            int e0 = half*32 + i*4;
            unsigned short b0 = f2bf(featf(k4.x)*mv);
            unsigned short b1 = f2bf(featf(k4.y)*mv);
            unsigned short b2 = f2bf(featf(k4.z)*mv);
            unsigned short b3 = f2bf(featf(k4.w)*mv);
            uint2 wv; wv.x = (unsigned)b0 | ((unsigned)b1 << 16);
            wv.y = (unsigned)b2 | ((unsigned)b3 << 16);
            *(uint2*)&kT[KT_IDX(s2, e0)] = wv;
        }
        #pragma unroll
        for (int i = 0; i < 8; ++i) {
            float4 v4 = *(const float4*)(vrow + i*4);
            int m0 = half*32 + i*4;
            vT[VT_IDX(m0+0, s2)] = f2bf(v4.x);
            vT[VT_IDX(m0+1, s2)] = f2bf(v4.y);
            vT[VT_IDX(m0+2, s2)] = f2bf(v4.z);
            vT[VT_IDX(m0+3, s2)] = f2bf(v4.w);
        }
    }
    {
        const int e  = tid >> 2;          // 0..63
        const int m0 = (tid & 3) * 16;
        const float* sp = kv_prefix + (size_t)b*EE*MM  + (size_t)e*MM + m0;
        const float* gp = kv_total  + (size_t)nh*EE*MM + (size_t)e*MM + m0;
        #pragma unroll
        for (int i4 = 0; i4 < 4; ++i4) {
            float4 s4 = *(const float4*)(sp + i4*4);
            float4 g4 = *(const float4*)(gp + i4*4);
            int mb = m0 + i4*4;
            sT[ST_IDX(mb+0, e)] = f2bf(s4.x);  gT[ST_IDX(mb+0, e)] = f2bf(g4.x);
            sT[ST_IDX(mb+1, e)] = f2bf(s4.y);  gT[ST_IDX(mb+1, e)] = f2bf(g4.y);
            sT[ST_IDX(mb+2, e)] = f2bf(s4.z);  gT[ST_IDX(mb+2, e)] = f2bf(g4.z);
            sT[ST_IDX(mb+3, e)] = f2bf(s4.w);  gT[ST_IDX(mb+3, e)] = f2bf(g4.w);
        }
    }
    if (tid < EE) {
        kspS[tid] = ksum_prefix[(size_t)b*EE + tid];
        kstS[tid] = ksum_total[(size_t)nh*EE + tid];
    }
    __syncthreads();

    // ---- per-wave compute ----
    const int w    = tid >> 6;
    const int lane = tid & 63;
    const int rho  = lane & 31;
    const int hi   = lane >> 5;
    const int tch  = w + 4*rho;           // this lane's t-row

    short8 qf[4];
    float zcI = 0.f, znI = 0.f;           // fp32 inter dots (half-lane partial)
    {
        const float* qrow = qin + base + (size_t)tch*rowstride;
        #pragma unroll
        for (int ks = 0; ks < 4; ++ks) {
            int e0 = ks*16 + hi*8;
            float4 a = *(const float4*)(qrow + e0);
            float4 d = *(const float4*)(qrow + e0 + 4);
            float qv0 = featf(a.x), qv1 = featf(a.y), qv2 = featf(a.z), qv3 = featf(a.w);
            float qv4 = featf(d.x), qv5 = featf(d.y), qv6 = featf(d.z), qv7 = featf(d.w);
            zcI += qv0*kspS[e0+0] + qv1*kspS[e0+1] + qv2*kspS[e0+2] + qv3*kspS[e0+3]
                 + qv4*kspS[e0+4] + qv5*kspS[e0+5] + qv6*kspS[e0+6] + qv7*kspS[e0+7];
            znI += qv0*kstS[e0+0] + qv1*kstS[e0+1] + qv2*kstS[e0+2] + qv3*kstS[e0+3]
                 + qv4*kstS[e0+4] + qv5*kstS[e0+5] + qv6*kstS[e0+6] + qv7*kstS[e0+7];
            short8 f;
            f[0] = (short)f2bf(qv0); f[1] = (short)f2bf(qv1);
            f[2] = (short)f2bf(qv2); f[3] = (short)f2bf(qv3);
            f[4] = (short)f2bf(qv4); f[5] = (short)f2bf(qv5);
            f[6] = (short)f2bf(qv6); f[7] = (short)f2bf(qv7);
            qf[ks] = f;
        }
    }

    f32x16 accC0 = ZERO16, accC1 = ZERO16, accN0 = ZERO16, accN1 = ZERO16;
    float zcs = 0.f;                       // masked intra score sum (half partial)

    // ---- intra-chunk: QK^T -> mask -> P -> PV, per 32-wide s-tile ----
    #pragma unroll
    for (int st = 0; st < 4; ++st) {
        short8 kf0 = *(const short8*)&kT[KT_IDX(st*32 + rho,  0 + hi*8)];
        short8 kf1 = *(const short8*)&kT[KT_IDX(st*32 + rho, 16 + hi*8)];
        short8 kf2 = *(const short8*)&kT[KT_IDX(st*32 + rho, 32 + hi*8)];
        short8 kf3 = *(const short8*)&kT[KT_IDX(st*32 + rho, 48 + hi*8)];

        f32x16 d = ZERO16;
        d = __builtin_amdgcn_mfma_f32_32x32x16_bf16(kf0, qf[0], d, 0, 0, 0);
        d = __builtin_amdgcn_mfma_f32_32x32x16_bf16(kf1, qf[1], d, 0, 0, 0);
        d = __builtin_amdgcn_mfma_f32_32x32x16_bf16(kf2, qf[2], d, 0, 0, 0);
        d = __builtin_amdgcn_mfma_f32_32x32x16_bf16(kf3, qf[3], d, 0, 0, 0);

        float pm[16];
        #pragma unroll
        for (int r = 0; r < 16; ++r) {
            int sl  = (r&3) + 8*(r>>2) + 4*hi;
            int sch = st*32 + sl;
            float vv = (sch <= tch) ? d[r] : 0.f;
            pm[r] = vv;
            zcs += vv;
        }

        unsigned c01 = cvtpk(pm[0],  pm[1]),  c23 = cvtpk(pm[2],  pm[3]);
        unsigned c45 = cvtpk(pm[4],  pm[5]),  c67 = cvtpk(pm[6],  pm[7]);
        plswap(c01, c45); plswap(c23, c67);
        unsigned c89 = cvtpk(pm[8],  pm[9]),  cab = cvtpk(pm[10], pm[11]);
        unsigned ccd = cvtpk(pm[12], pm[13]), cef = cvtpk(pm[14], pm[15]);
        plswap(c89, ccd); plswap(cab, cef);

        union { unsigned u[4]; short8 s; } uA, uB;
        uA.u[0] = c01; uA.u[1] = c23; uA.u[2] = c45; uA.u[3] = c67;   // k = s 0..15
        uB.u[0] = c89; uB.u[1] = cab; uB.u[2] = ccd; uB.u[3] = cef;   // k = s 16..31
        short8 paA = uA.s, paB = uB.s;

        {
            short8 v0 = *(const short8*)&vT[VT_IDX( 0 + rho, st*32 +  0 + hi*8)];
            short8 v1 = *(const short8*)&vT[VT_IDX( 0 + rho, st*32 + 16 + hi*8)];
            accC0 = __builtin_amdgcn_mfma_f32_32x32x16_bf16(paA, v0, accC0, 0, 0, 0);
            accC0 = __builtin_amdgcn_mfma_f32_32x32x16_bf16(paB, v1, accC0, 0, 0, 0);
        }
        {
            short8 v0 = *(const short8*)&vT[VT_IDX(32 + rho, st*32 +  0 + hi*8)];
            short8 v1 = *(const short8*)&vT[VT_IDX(32 + rho, st*32 + 16 + hi*8)];
            accC1 = __builtin_amdgcn_mfma_f32_32x32x16_bf16(paA, v0, accC1, 0, 0, 0);
            accC1 = __builtin_amdgcn_mfma_f32_32x32x16_bf16(paB, v1, accC1, 0, 0, 0);
        }
    }

    // ---- inter-chunk (A = Q, B = S^T / G^T) ----
    #pragma unroll
    for (int ks = 0; ks < 4; ++ks) {
        int e0 = ks*16 + hi*8;
        short8 sf0 = *(const short8*)&sT[ST_IDX( 0 + rho, e0)];
        short8 sf1 = *(const short8*)&sT[ST_IDX(32 + rho, e0)];
        short8 gf0 = *(const short8*)&gT[ST_IDX( 0 + rho, e0)];
        short8 gf1 = *(const short8*)&gT[ST_IDX(32 + rho, e0)];
        accC0 = __builtin_amdgcn_mfma_f32_32x32x16_bf16(qf[ks], sf0, accC0, 0, 0, 0);
        accC1 = __builtin_amdgcn_mfma_f32_32x32x16_bf16(qf[ks], sf1, accC1, 0, 0, 0);
        accN0 = __builtin_amdgcn_mfma_f32_32x32x16_bf16(qf[ks], gf0, accN0, 0, 0, 0);
        accN1 = __builtin_amdgcn_mfma_f32_32x32x16_bf16(qf[ks], gf1, accN1, 0, 0, 0);
    }

    // ---- denominators (cross-half reduce; lanes l and l+32 share t-row) ----
    float zc = zcs + zcI;
    zc += __shfl_xor(zc, 32, 64);
    float zn = znI;
    zn += __shfl_xor(zn, 32, 64);
    float zci = 1.f / (zc + FEPS);
    float zni = 1.f / (zn + FEPS);

    // ---- epilogue ----
    #pragma unroll
    for (int r = 0; r < 16; ++r) {
        int rrow = (r&3) + 8*(r>>2) + 4*hi;
        float zcr = __shfl(zci, rrow, 64);
        float znr = __shfl(zni, rrow, 64);
        int t = w + 4*rrow;
        size_t ob = ((size_t)(n*LL + c*TT + t)*HH + h)*MM;
        outVc[ob +      rho] = accC0[r] * zcr;
        outVc[ob + 32 + rho] = accC1[r] * zcr;
        outV [ob +      rho] = accN0[r] * znr;
        outV [ob + 32 + rho] = accN1[r] * znr;
    }
}

// ---------------------------------------------------------------------------
extern "C" void kernel_launch(void* const* d_in, const int* in_sizes, int n_in,
                              void* d_out, int out_size, void* d_ws, size_t ws_size,
                              hipStream_t stream) {
    const float* q    = (const float*)d_in[0];
    const float* k    = (const float*)d_in[1];
    const float* v    = (const float*)d_in[2];
    const float* mask = (const float*)d_in[3];

    float* outV  = (float*)d_out;
    float* outVc = outV + (size_t)NN*LL*HH*MM;

    float* kv_chunk   = (float*)d_ws;                               // N*H*C*E*M
    float* ksum_chunk = kv_chunk   + (size_t)NN*HH*CC*EE*MM;        // N*H*C*E
    float* kv_total   = ksum_chunk + (size_t)NN*HH*CC*EE;           // N*H*E*M
    float* ksum_total = kv_total   + (size_t)NN*HH*EE*MM;           // N*H*E

    k_chunk_sums<<<NN*HH*CC, 256, 0, stream>>>(k, v, mask, kv_chunk, ksum_chunk);
    k_scan_kv  <<<NN*HH*16, 256, 0, stream>>>(kv_chunk, kv_total);
    k_scan_ksum<<<NN*HH,     64, 0, stream>>>(ksum_chunk, ksum_total);
    k_output   <<<NN*HH*CC, 256, 0, stream>>>(q, k, v, mask,
                                              kv_chunk, ksum_chunk,
                                              kv_total, ksum_total,
                                              outV, outVc);
}

// Round 10
// 190.280 us; speedup vs baseline: 9.7392x; 1.0403x over previous
//
#include <hip/hip_runtime.h>

#define NN 2
#define LL 8192
#define HH 8
#define EE 64
#define MM 64
#define TT 128
#define CC (LL/TT)   // 64 chunks
#define FEPS 1e-6f

typedef __attribute__((ext_vector_type(8)))  short short8;
typedef __attribute__((ext_vector_type(16))) float f32x16;

__device__ __forceinline__ float featf(float x) {
    return x > 0.f ? x + 1.f : __expf(x);   // elu(x)+1
}

__device__ __forceinline__ unsigned short f2bf(float x) {
    union { float f; unsigned u; } v; v.f = x;
    unsigned r = v.u + 0x7FFF + ((v.u >> 16) & 1);   // RNE
    return (unsigned short)(r >> 16);
}

__device__ __forceinline__ float bf2f(unsigned short x) {
    union { unsigned u; float f; } v; v.u = ((unsigned)x) << 16;
    return v.f;
}

__device__ __forceinline__ unsigned cvtpk(float lo, float hi) {
    unsigned r;
    asm volatile("v_cvt_pk_bf16_f32 %0, %1, %2" : "=v"(r) : "v"(lo), "v"(hi));
    return r;
}

__device__ __forceinline__ void plswap(unsigned &a, unsigned &b) {
    asm volatile("v_permlane32_swap_b32 %0, %1" : "+v"(a), "+v"(b));
}

__device__ __forceinline__ void dma16(const unsigned short* g, unsigned short* l) {
    __builtin_amdgcn_global_load_lds(
        (const __attribute__((address_space(1))) unsigned int*)(g),
        (__attribute__((address_space(3))) unsigned int*)(l), 16, 0, 0);
}

#define ZERO16 {0.f,0.f,0.f,0.f,0.f,0.f,0.f,0.f,0.f,0.f,0.f,0.f,0.f,0.f,0.f,0.f}

// XOR-swizzled LDS index macros (u16 units; XOR of idx bits 3-5 = 16B groups)
#define KT_IDX(s,e)  ((((s)*64)  + (e)) ^ (((s)&7)<<3))   // [s][e]
#define KTT_IDX(e,s) ((((e)*128) + (s)) ^ (((e)&7)<<3))   // [e][s]
#define VT_IDX(m,s)  ((((m)*128) + (s)) ^ (((m)&7)<<3))   // [m][s]
#define ST_IDX(m,e)  ((((m)*64)  + (e)) ^ (((m)&7)<<3))   // [m][e]

// ---------------------------------------------------------------------------
// Kernel A: per-(n,h,chunk): MFMA chunk sums kv_chunkT[m][e] = sum_t V[t][m]K[t][e],
// ksum_chunk[e] = sum_t K[t][e]; ALSO emits pre-swizzled bf16 images:
//   Kimg = kT-layout [s][e] (featured+masked), Vimg = vT-layout [m][s].
// grid = N*H*C, block = 256.
// ---------------------------------------------------------------------------
__global__ __launch_bounds__(256) void k_chunk_sums(
    const float* __restrict__ kin, const float* __restrict__ vin,
    const float* __restrict__ mask,
    unsigned short* __restrict__ Kimg, unsigned short* __restrict__ Vimg,
    float* __restrict__ kv_chunkT, float* __restrict__ ksum_chunk)
{
    __shared__ unsigned short kTT[EE*TT];  // [e][s] swizzled, 16 KB
    __shared__ unsigned short vTl[MM*TT];  // [m][s] swizzled, 16 KB

    const int b  = blockIdx.x;
    const int c  = b % CC;
    const int nh = b / CC;
    const int h  = nh % HH;
    const int n  = nh / HH;
    const int tid = threadIdx.x;

    const size_t rowstride = (size_t)HH * EE;
    const size_t base = ((size_t)(n*LL + c*TT) * HH + h) * EE;

    const int s2 = tid >> 1, half = tid & 1;
    const float mv = mask[n*LL + c*TT + s2];
    const float* krow = kin + base + (size_t)s2*rowstride + half*32;
    const float* vrow = vin + base + (size_t)s2*rowstride + half*32;
    unsigned short* kdst = Kimg + (size_t)b*(TT*EE);

    #pragma unroll
    for (int i = 0; i < 8; ++i) {
        float4 k4 = *(const float4*)(krow + i*4);
        int e0 = half*32 + i*4;
        unsigned short b0 = f2bf(featf(k4.x)*mv), b1 = f2bf(featf(k4.y)*mv);
        unsigned short b2 = f2bf(featf(k4.z)*mv), b3 = f2bf(featf(k4.w)*mv);
        uint2 wv; wv.x = (unsigned)b0 | ((unsigned)b1 << 16);
        wv.y = (unsigned)b2 | ((unsigned)b3 << 16);
        *(uint2*)(kdst + KT_IDX(s2, e0)) = wv;           // Kimg direct (pre-swizzled)
        kTT[KTT_IDX(e0+0, s2)] = b0;
        kTT[KTT_IDX(e0+1, s2)] = b1;
        kTT[KTT_IDX(e0+2, s2)] = b2;
        kTT[KTT_IDX(e0+3, s2)] = b3;
    }
    #pragma unroll
    for (int i = 0; i < 8; ++i) {
        float4 v4 = *(const float4*)(vrow + i*4);
        int m0 = half*32 + i*4;
        vTl[VT_IDX(m0+0, s2)] = f2bf(v4.x);
        vTl[VT_IDX(m0+1, s2)] = f2bf(v4.y);
        vTl[VT_IDX(m0+2, s2)] = f2bf(v4.z);
        vTl[VT_IDX(m0+3, s2)] = f2bf(v4.w);
    }
    __syncthreads();

    // Vimg bulk copy (coalesced both sides)
    {
        uint4* d = (uint4*)(Vimg + (size_t)b*(MM*TT));
        const uint4* s = (const uint4*)vTl;
        #pragma unroll
        for (int j = 0; j < 4; ++j) d[tid + j*256] = s[tid + j*256];
    }

    // MFMA: D[m][e] = sum_t V[t][m] K[t][e]; wave w -> quadrant (mq=w>>1, eq=w&1)
    const int w = tid >> 6, lane = tid & 63, rho = lane & 31, hi = lane >> 5;
    const int mq = w >> 1, eq = w & 1;
    f32x16 acc = ZERO16;
    #pragma unroll
    for (int ks = 0; ks < 8; ++ks) {
        int t0 = ks*16 + hi*8;
        short8 va = *(const short8*)&vTl[VT_IDX(mq*32 + rho, t0)];
        short8 kb = *(const short8*)&kTT[KTT_IDX(eq*32 + rho, t0)];
        acc = __builtin_amdgcn_mfma_f32_32x32x16_bf16(va, kb, acc, 0, 0, 0);
    }
    float* kvdst = kv_chunkT + (size_t)b*(EE*MM);
    #pragma unroll
    for (int r = 0; r < 16; ++r) {
        int m = mq*32 + (r&3) + 8*(r>>2) + 4*hi;
        kvdst[m*64 + eq*32 + rho] = acc[r];
    }

    // ksum[e] = sum_s K[s][e] (from bf16 values — consistent with MFMA path)
    if (tid < EE) {
        float s = 0.f;
        #pragma unroll
        for (int j = 0; j < 16; ++j) {
            short8 kk8 = *(const short8*)&kTT[KTT_IDX(tid, j*8)];
            #pragma unroll
            for (int x = 0; x < 8; ++x) s += bf2f((unsigned short)kk8[x]);
        }
        ksum_chunk[(size_t)b*EE + tid] = s;
    }
}

// ---------------------------------------------------------------------------
// Kernel B: fused exclusive prefix scans. kv: thread owns (m,e); reads
// kv_chunkT coalesced, writes pre-swizzled bf16 S^T/G^T images coalesced.
// part==0 blocks also scan ksum (fp32). grid = N*H*16, block = 256.
// ---------------------------------------------------------------------------
__global__ __launch_bounds__(256) void k_scan(
    const float* __restrict__ kv_chunkT, const float* __restrict__ ksum_chunk,
    unsigned short* __restrict__ Simg, unsigned short* __restrict__ Gimg,
    float* __restrict__ ksum_prefix, float* __restrict__ ksum_total)
{
    const int part = blockIdx.x & 15, nh = blockIdx.x >> 4;
    const int tid = threadIdx.x;
    const int m = part*4 + (tid >> 6), e = tid & 63;

    const float* src = kv_chunkT + (size_t)nh*CC*EE*MM + m*64 + e;
    float vals[CC];
    #pragma unroll
    for (int c = 0; c < CC; ++c) vals[c] = src[(size_t)c*EE*MM];

    unsigned short* sdst = Simg + (size_t)nh*CC*EE*MM + ST_IDX(m, e);
    float run = 0.f;
    #pragma unroll
    for (int c = 0; c < CC; ++c) { sdst[(size_t)c*EE*MM] = f2bf(run); run += vals[c]; }
    Gimg[(size_t)nh*EE*MM + ST_IDX(m, e)] = f2bf(run);

    if (part == 0 && tid < EE) {
        const float* ks = ksum_chunk + (size_t)nh*CC*EE + tid;
        float kv[CC];
        #pragma unroll
        for (int c = 0; c < CC; ++c) kv[c] = ks[c*EE];
        float r2 = 0.f;
        float* kp = ksum_prefix + (size_t)nh*CC*EE + tid;
        #pragma unroll
        for (int c = 0; c < CC; ++c) { kp[c*EE] = r2; r2 += kv[c]; }
        ksum_total[nh*EE + tid] = r2;
    }
}

// ---------------------------------------------------------------------------
// Kernel C (k_output): DMA-staged from pre-swizzled images; compute loop
// identical to verified round-5 kernel.
// ---------------------------------------------------------------------------
__global__ __launch_bounds__(256) void k_output(
    const float* __restrict__ qin,
    const unsigned short* __restrict__ Kimg, const unsigned short* __restrict__ Vimg,
    const unsigned short* __restrict__ Simg, const unsigned short* __restrict__ Gimg,
    const float* __restrict__ ksum_prefix,  const float* __restrict__ ksum_total,
    float* __restrict__ outV, float* __restrict__ outVc)
{
    __shared__ unsigned short kT[TT*EE];   // [s][e] bf16, swizzled, 16 KB
    __shared__ unsigned short vT[MM*TT];   // [m][s] bf16, swizzled, 16 KB
    __shared__ unsigned short sT[MM*EE];   // [m][e] bf16 (S_prefix^T), 8 KB
    __shared__ unsigned short gT[MM*EE];   // [m][e] bf16 (KV_total^T), 8 KB
    __shared__ float kspS[EE];
    __shared__ float kstS[EE];

    const int b  = blockIdx.x;
    const int c  = b % CC;
    const int nh = b / CC;
    const int h  = nh % HH;
    const int n  = nh / HH;
    const int tid = threadIdx.x;

    const size_t rowstride = (size_t)HH * EE;
    const size_t base = ((size_t)(n*LL + c*TT) * HH + h) * EE;

    // ---- DMA staging from pre-swizzled images ----
    {
        const unsigned short* kimg = Kimg + (size_t)b*(TT*EE);
        const unsigned short* vimg = Vimg + (size_t)b*(MM*TT);
        const unsigned short* simg = Simg + (size_t)b*(EE*MM);
        const unsigned short* gimg = Gimg + (size_t)nh*(EE*MM);
        const int wid = tid >> 6, ln = tid & 63;
        #pragma unroll
        for (int kk = 0; kk < 4; ++kk) {
            dma16(kimg + (wid*4+kk)*512 + ln*8, &kT[(wid*4+kk)*512]);
            dma16(vimg + (wid*4+kk)*512 + ln*8, &vT[(wid*4+kk)*512]);
        }
        #pragma unroll
        for (int kk = 0; kk < 2; ++kk) {
            dma16(simg + (wid*2+kk)*512 + ln*8, &sT[(wid*2+kk)*512]);
            dma16(gimg + (wid*2+kk)*512 + ln*8, &gT[(wid*2+kk)*512]);
        }
    }
    if (tid < EE) {
        kspS[tid] = ksum_prefix[(size_t)b*EE + tid];
        kstS[tid] = ksum_total[(size_t)nh*EE + tid];
    }
    __syncthreads();

    // ---- per-wave compute (identical to round 5) ----
    const int w    = tid >> 6;
    const int lane = tid & 63;
    const int rho  = lane & 31;
    const int hi   = lane >> 5;
    const int tch  = w + 4*rho;

    short8 qf[4];
    float zcI = 0.f, znI = 0.f;
    {
        const float* qrow = qin + base + (size_t)tch*rowstride;
        #pragma unroll
        for (int ks = 0; ks < 4; ++ks) {
            int e0 = ks*16 + hi*8;
            float4 a = *(const float4*)(qrow + e0);
            float4 d = *(const float4*)(qrow + e0 + 4);
            float qv0 = featf(a.x), qv1 = featf(a.y), qv2 = featf(a.z), qv3 = featf(a.w);
            float qv4 = featf(d.x), qv5 = featf(d.y), qv6 = featf(d.z), qv7 = featf(d.w);
            zcI += qv0*kspS[e0+0] + qv1*kspS[e0+1] + qv2*kspS[e0+2] + qv3*kspS[e0+3]
                 + qv4*kspS[e0+4] + qv5*kspS[e0+5] + qv6*kspS[e0+6] + qv7*kspS[e0+7];
            znI += qv0*kstS[e0+0] + qv1*kstS[e0+1] + qv2*kstS[e0+2] + qv3*kstS[e0+3]
                 + qv4*kstS[e0+4] + qv5*kstS[e0+5] + qv6*kstS[e0+6] + qv7*kstS[e0+7];
            short8 f;
            f[0] = (short)f2bf(qv0); f[1] = (short)f2bf(qv1);
            f[2] = (short)f2bf(qv2); f[3] = (short)f2bf(qv3);
            f[4] = (short)f2bf(qv4); f[5] = (short)f2bf(qv5);
            f[6] = (short)f2bf(qv6); f[7] = (short)f2bf(qv7);
            qf[ks] = f;
        }
    }

    f32x16 accC0 = ZERO16, accC1 = ZERO16, accN0 = ZERO16, accN1 = ZERO16;
    float zcs = 0.f;

    #pragma unroll
    for (int st = 0; st < 4; ++st) {
        short8 kf0 = *(const short8*)&kT[KT_IDX(st*32 + rho,  0 + hi*8)];
        short8 kf1 = *(const short8*)&kT[KT_IDX(st*32 + rho, 16 + hi*8)];
        short8 kf2 = *(const short8*)&kT[KT_IDX(st*32 + rho, 32 + hi*8)];
        short8 kf3 = *(const short8*)&kT[KT_IDX(st*32 + rho, 48 + hi*8)];

        f32x16 d = ZERO16;
        d = __builtin_amdgcn_mfma_f32_32x32x16_bf16(kf0, qf[0], d, 0, 0, 0);
        d = __builtin_amdgcn_mfma_f32_32x32x16_bf16(kf1, qf[1], d, 0, 0, 0);
        d = __builtin_amdgcn_mfma_f32_32x32x16_bf16(kf2, qf[2], d, 0, 0, 0);
        d = __builtin_amdgcn_mfma_f32_32x32x16_bf16(kf3, qf[3], d, 0, 0, 0);

        float pm[16];
        #pragma unroll
        for (int r = 0; r < 16; ++r) {
            int sl  = (r&3) + 8*(r>>2) + 4*hi;
            int sch = st*32 + sl;
            float vv = (sch <= tch) ? d[r] : 0.f;
            pm[r] = vv;
            zcs += vv;
        }

        unsigned c01 = cvtpk(pm[0],  pm[1]),  c23 = cvtpk(pm[2],  pm[3]);
        unsigned c45 = cvtpk(pm[4],  pm[5]),  c67 = cvtpk(pm[6],  pm[7]);
        plswap(c01, c45); plswap(c23, c67);
        unsigned c89 = cvtpk(pm[8],  pm[9]),  cab = cvtpk(pm[10], pm[11]);
        unsigned ccd = cvtpk(pm[12], pm[13]), cef = cvtpk(pm[14], pm[15]);
        plswap(c89, ccd); plswap(cab, cef);

        union { unsigned u[4]; short8 s; } uA, uB;
        uA.u[0] = c01; uA.u[1] = c23; uA.u[2] = c45; uA.u[3] = c67;
        uB.u[0] = c89; uB.u[1] = cab; uB.u[2] = ccd; uB.u[3] = cef;
        short8 paA = uA.s, paB = uB.s;

        {
            short8 v0 = *(const short8*)&vT[VT_IDX( 0 + rho, st*32 +  0 + hi*8)];
            short8 v1 = *(const short8*)&vT[VT_IDX( 0 + rho, st*32 + 16 + hi*8)];
            accC0 = __builtin_amdgcn_mfma_f32_32x32x16_bf16(paA, v0, accC0, 0, 0, 0);
            accC0 = __builtin_amdgcn_mfma_f32_32x32x16_bf16(paB, v1, accC0, 0, 0, 0);
        }
        {
            short8 v0 = *(const short8*)&vT[VT_IDX(32 + rho, st*32 +  0 + hi*8)];
            short8 v1 = *(const short8*)&vT[VT_IDX(32 + rho, st*32 + 16 + hi*8)];
            accC1 = __builtin_amdgcn_mfma_f32_32x32x16_bf16(paA, v0, accC1, 0, 0, 0);
            accC1 = __builtin_amdgcn_mfma_f32_32x32x16_bf16(paB, v1, accC1, 0, 0, 0);
        }
    }

    #pragma unroll
    for (int ks = 0; ks < 4; ++ks) {
        int e0 = ks*16 + hi*8;
        short8 sf0 = *(const short8*)&sT[ST_IDX( 0 + rho, e0)];
        short8 sf1 = *(const short8*)&sT[ST_IDX(32 + rho, e0)];
        short8 gf0 = *(const short8*)&gT[ST_IDX( 0 + rho, e0)];
        short8 gf1 = *(const short8*)&gT[ST_IDX(32 + rho, e0)];
        accC0 = __builtin_amdgcn_mfma_f32_32x32x16_bf16(qf[ks], sf0, accC0, 0, 0, 0);
        accC1 = __builtin_amdgcn_mfma_f32_32x32x16_bf16(qf[ks], sf1, accC1, 0, 0, 0);
        accN0 = __builtin_amdgcn_mfma_f32_32x32x16_bf16(qf[ks], gf0, accN0, 0, 0, 0);
        accN1 = __builtin_amdgcn_mfma_f32_32x32x16_bf16(qf[ks], gf1, accN1, 0, 0, 0);
    }

    float zc = zcs + zcI;
    zc += __shfl_xor(zc, 32, 64);
    float zn = znI;
    zn += __shfl_xor(zn, 32, 64);
    float zci = 1.f / (zc + FEPS);
    float zni = 1.f / (zn + FEPS);

    #pragma unroll
    for (int r = 0; r < 16; ++r) {
        int rrow = (r&3) + 8*(r>>2) + 4*hi;
        float zcr = __shfl(zci, rrow, 64);
        float znr = __shfl(zni, rrow, 64);
        int t = w + 4*rrow;
        size_t ob = ((size_t)(n*LL + c*TT + t)*HH + h)*MM;
        outVc[ob +      rho] = accC0[r] * zcr;
        outVc[ob + 32 + rho] = accC1[r] * zcr;
        outV [ob +      rho] = accN0[r] * znr;
        outV [ob + 32 + rho] = accN1[r] * znr;
    }
}

// ---------------------------------------------------------------------------
extern "C" void kernel_launch(void* const* d_in, const int* in_sizes, int n_in,
                              void* d_out, int out_size, void* d_ws, size_t ws_size,
                              hipStream_t stream) {
    const float* q    = (const float*)d_in[0];
    const float* k    = (const float*)d_in[1];
    const float* v    = (const float*)d_in[2];
    const float* mask = (const float*)d_in[3];

    float* outV  = (float*)d_out;
    float* outVc = outV + (size_t)NN*LL*HH*MM;

    char* ws = (char*)d_ws;
    float*          kv_chunkT   = (float*)(ws);                      // 16,777,216 B
    unsigned short* Kimg        = (unsigned short*)(ws + 16777216);  // 16,777,216 B
    unsigned short* Vimg        = (unsigned short*)(ws + 33554432);  // 16,777,216 B
    unsigned short* Simg        = (unsigned short*)(ws + 50331648);  //  8,388,608 B
    unsigned short* Gimg        = (unsigned short*)(ws + 58720256);  //    131,072 B
    float*          ksum_chunk  = (float*)(ws + 58851328);           //    262,144 B
    float*          ksum_prefix = (float*)(ws + 59113472);           //    262,144 B
    float*          ksum_total  = (float*)(ws + 59375616);           //      4,096 B

    k_chunk_sums<<<NN*HH*CC, 256, 0, stream>>>(k, v, mask, Kimg, Vimg,
                                               kv_chunkT, ksum_chunk);
    k_scan      <<<NN*HH*16, 256, 0, stream>>>(kv_chunkT, ksum_chunk,
                                               Simg, Gimg, ksum_prefix, ksum_total);
    k_output    <<<NN*HH*CC, 256, 0, stream>>>(q, Kimg, Vimg, Simg, Gimg,
                                               ksum_prefix, ksum_total,
                                               outV, outVc);
}